// Round 10
// baseline (6536.147 us; speedup 1.0000x reference)
//
#include <hip/hip_runtime.h>

#define HD 64
#define KP 16            // timesteps per phase (one workgroup barrier per phase)
#define NS 32            // ring slots = 2 phases (double buffer)
#define L2E 1.4426950408889634f

typedef _Float16 v2h __attribute__((ext_vector_type(2)));
typedef _Float16 h8  __attribute__((ext_vector_type(8)));

__device__ __forceinline__ float fexp2(float x) { return __builtin_amdgcn_exp2f(x); }
__device__ __forceinline__ float frcp(float x)  { return __builtin_amdgcn_rcpf(x); }
__device__ __forceinline__ float ftanh_fast(float x) {
    return 1.f - 2.f * frcp(fexp2(2.f * L2E * x) + 1.f);
}
__device__ __forceinline__ float fsig(float x) {
    return frcp(fexp2(-L2E * x) + 1.f);
}

#if __has_builtin(__builtin_amdgcn_fdot2)
__device__ __forceinline__ float FDOT2(v2h a, v2h b, float c) {
    return __builtin_amdgcn_fdot2(a, b, c, false);
}
#else
__device__ __forceinline__ float FDOT2(v2h a, v2h b, float c) {
    return fmaf((float)a.x, (float)b.x, fmaf((float)a.y, (float)b.y, c));
}
#endif

// R9 post-mortem: weight-placement ladder is monotone BAD toward LDS
// (global-remat 977 -> half-LDS 1234 -> all-LDS 1676 us): DS-pipe reads
// serialize into the dep chain; the global/L1 path pipelines. R2's remaining
// ~300-380 cy/step tax is NOT the reloads (h-independent, prefetchable) but
// the REMATERIALIZED f32->f16 convert+pack VALU chain (2 ops/pair x 128
// pairs) on the critical SIMD. Fix: pre-convert all three weight matrices
// to f16 ONCE (prep kernel -> d_ws). In-loop weight refs become plain
// f16 b128 loads: remat is free, zero convert VALU. Same RNE cast, same
// accumulation pairing -> bitwise-identical results.

// 4-gate 64-dot: h8 chunks of h x f16 weight rows (global, L1/L2-hot).
// Pairing matches R2 exactly: pairs (4q,4q+1,4q+2,4q+3) -> (a0,a1,a0,a1).
#define DOTW4(HP, PA, PB, PC, PD) do { \
    _Pragma("unroll") \
    for (int q = 0; q < 8; ++q) { \
        h8 hv_ = (HP)[q]; \
        v2h p0_={hv_[0],hv_[1]}, p1_={hv_[2],hv_[3]}; \
        v2h p2_={hv_[4],hv_[5]}, p3_={hv_[6],hv_[7]}; \
        h8 wa_ = (PA)[q], wb_ = (PB)[q], wc_ = (PC)[q], wd_ = (PD)[q]; \
        a00=FDOT2(v2h{wa_[0],wa_[1]},p0_,a00); a01=FDOT2(v2h{wa_[2],wa_[3]},p1_,a01); \
        a00=FDOT2(v2h{wa_[4],wa_[5]},p2_,a00); a01=FDOT2(v2h{wa_[6],wa_[7]},p3_,a01); \
        a10=FDOT2(v2h{wb_[0],wb_[1]},p0_,a10); a11=FDOT2(v2h{wb_[2],wb_[3]},p1_,a11); \
        a10=FDOT2(v2h{wb_[4],wb_[5]},p2_,a10); a11=FDOT2(v2h{wb_[6],wb_[7]},p3_,a11); \
        a20=FDOT2(v2h{wc_[0],wc_[1]},p0_,a20); a21=FDOT2(v2h{wc_[2],wc_[3]},p1_,a21); \
        a20=FDOT2(v2h{wc_[4],wc_[5]},p2_,a20); a21=FDOT2(v2h{wc_[6],wc_[7]},p3_,a21); \
        a30=FDOT2(v2h{wd_[0],wd_[1]},p0_,a30); a31=FDOT2(v2h{wd_[2],wd_[3]},p1_,a31); \
        a30=FDOT2(v2h{wd_[4],wd_[5]},p2_,a30); a31=FDOT2(v2h{wd_[6],wd_[7]},p3_,a31); \
    } } while (0)

// 2-gate variant (xproj waves).
#define DOTW2(HP, PA, PB) do { \
    _Pragma("unroll") \
    for (int q = 0; q < 8; ++q) { \
        h8 hv_ = (HP)[q]; \
        v2h p0_={hv_[0],hv_[1]}, p1_={hv_[2],hv_[3]}; \
        v2h p2_={hv_[4],hv_[5]}, p3_={hv_[6],hv_[7]}; \
        h8 wa_ = (PA)[q], wb_ = (PB)[q]; \
        a00=FDOT2(v2h{wa_[0],wa_[1]},p0_,a00); a01=FDOT2(v2h{wa_[2],wa_[3]},p1_,a01); \
        a00=FDOT2(v2h{wa_[4],wa_[5]},p2_,a00); a01=FDOT2(v2h{wa_[6],wa_[7]},p3_,a01); \
        a10=FDOT2(v2h{wb_[0],wb_[1]},p0_,a10); a11=FDOT2(v2h{wb_[2],wb_[3]},p1_,a11); \
        a10=FDOT2(v2h{wb_[4],wb_[5]},p2_,a10); a11=FDOT2(v2h{wb_[6],wb_[7]},p3_,a11); \
    } } while (0)

// ---- prep: convert the 3 [256][64] f32 weight matrices to f16 in d_ws ----
__global__ void prep_kernel(const float* __restrict__ Whh0,
                            const float* __restrict__ Whh1,
                            const float* __restrict__ Wih1,
                            _Float16* __restrict__ wf)
{
    const int i = blockIdx.x * 256 + threadIdx.x;      // 0..16383
    wf[i]             = (_Float16)Whh0[i];
    wf[16384 + i]     = (_Float16)Whh1[i];
    wf[2 * 16384 + i] = (_Float16)Wih1[i];
}

// 4 waves (1 per SIMD), one block per batch element:
//   w0 (A): layer-0 recurrence (lane = hidden unit, all 4 gates in-lane).
//   w1 (C): layer-1 recurrence, lag 2 phases; stores f32 h for head.
//   w2 (B0): layer-1 xproj gates i,f, lag 1 phase.
//   w3 (B1): layer-1 xproj gates g,o, lag 1 + output head, lag 3.
// Workgroup barrier once per KP=16 steps; rings double-buffered by phase.
__global__ __launch_bounds__(256)
void lstm2_kernel(const float* __restrict__ x,     // [B,T]
                  const float* __restrict__ h0in,  // [2,B,HD]
                  const float* __restrict__ c0in,  // [2,B,HD]
                  const float* __restrict__ Wih0,  // [4H,1]
                  const float* __restrict__ bih0,
                  const float* __restrict__ bhh0,
                  const float* __restrict__ bih1,
                  const float* __restrict__ bhh1,
                  const float* __restrict__ Wlin,  // [1,HD]
                  const float* __restrict__ blin,  // [1]
                  const _Float16* __restrict__ wf, // [3][256][64] f16 (d_ws)
                  float* __restrict__ out,         // [B,T]
                  int B, int T)
{
    const int b    = blockIdx.x;
    const int tid  = threadIdx.x;
    const int wave = __builtin_amdgcn_readfirstlane(tid >> 6);  // uniform (SGPR)
    const int lane = tid & 63;

    __shared__ __align__(16) _Float16 h0ring[NS][HD];        // layer-0 h (f16)
    __shared__ __align__(16) _Float16 h1ring[NS][HD];        // layer-1 h (f16)
    __shared__ __align__(16) float    h1f32[NS][HD + 4];     // layer-1 h (f32, head)
    __shared__ __align__(16) float    xpring[NS][4][HD];     // layer-1 xproj (f32)

    // ---- zero-init ALL LDS (launch-history independence), then barrier ----
    {
        _Float16* z0 = &h0ring[0][0];
        for (int i = tid; i < NS * HD; i += 256) z0[i] = (_Float16)0.f;
        _Float16* z1 = &h1ring[0][0];
        for (int i = tid; i < NS * HD; i += 256) z1[i] = (_Float16)0.f;
        float* z2 = &h1f32[0][0];
        for (int i = tid; i < NS * (HD + 4); i += 256) z2[i] = 0.f;
        float* z3 = &xpring[0][0][0];
        for (int i = tid; i < NS * 4 * HD; i += 256) z3[i] = 0.f;
    }
    __syncthreads();

    const int nphase = (T + KP - 1) / KP + 3;
    const _Float16* wfA = wf;                  // Whh0 f16
    const _Float16* wfC = wf + 16384;          // Whh1 f16
    const _Float16* wfX = wf + 2 * 16384;      // Wih1 f16

    if (wave == 0) {
        // ================= A: layer-0 recurrence =================
        const h8* pA = (const h8*)(wfA + (size_t)lane * HD);
        const h8* pB = (const h8*)(wfA + (size_t)(64 + lane) * HD);
        const h8* pC = (const h8*)(wfA + (size_t)(128 + lane) * HD);
        const h8* pD = (const h8*)(wfA + (size_t)(192 + lane) * HD);
        const float b0 = bih0[lane]       + bhh0[lane];
        const float b1 = bih0[64 + lane]  + bhh0[64 + lane];
        const float b2 = bih0[128 + lane] + bhh0[128 + lane];
        const float b3 = bih0[192 + lane] + bhh0[192 + lane];
        const float wx0 = Wih0[lane];       const float wx1 = Wih0[64 + lane];
        const float wx2 = Wih0[128 + lane]; const float wx3 = Wih0[192 + lane];
        float cst = c0in[b * HD + lane];
        h0ring[NS - 1][lane] = (_Float16)h0in[b * HD + lane];
        const float* xrow = x + (size_t)b * T;
        __syncthreads();

        for (int p = 0; p < nphase; ++p) {
            const int t0 = p * KP;
            if (t0 < T) {
                #pragma unroll 1
                for (int k = 0; k < KP; ++k) {
                    const int t = t0 + k;
                    if (t >= T) break;
                    const float xv = xrow[t];                   // uniform scalar load
                    const h8* hp = (const h8*)h0ring[(t + NS - 1) & (NS - 1)];
                    float a00 = b0, a01 = 0.f, a10 = b1, a11 = 0.f;
                    float a20 = b2, a21 = 0.f, a30 = b3, a31 = 0.f;
                    DOTW4(hp, pA, pB, pC, pD);
                    const float ai = fmaf(wx0, xv, a00 + a01);
                    const float af = fmaf(wx1, xv, a10 + a11);
                    const float ag = fmaf(wx2, xv, a20 + a21);
                    const float ao = fmaf(wx3, xv, a30 + a31);
                    const float iv = fsig(ai), fv = fsig(af);
                    const float gv = ftanh_fast(ag), ov = fsig(ao);
                    cst = fmaf(fv, cst, iv * gv);
                    const float h = ov * ftanh_fast(cst);
                    h0ring[t & (NS - 1)][lane] = (_Float16)h;   // same-wave roundtrip
                }
            }
            __syncthreads();
        }
    } else if (wave == 1) {
        // ================= C: layer-1 recurrence (lag 2 phases) =================
        const h8* pA = (const h8*)(wfC + (size_t)lane * HD);
        const h8* pB = (const h8*)(wfC + (size_t)(64 + lane) * HD);
        const h8* pC = (const h8*)(wfC + (size_t)(128 + lane) * HD);
        const h8* pD = (const h8*)(wfC + (size_t)(192 + lane) * HD);
        float cst = c0in[B * HD + b * HD + lane];
        h1ring[NS - 1][lane] = (_Float16)h0in[B * HD + b * HD + lane];
        __syncthreads();

        for (int p = 0; p < nphase; ++p) {
            const int t0 = (p - 2) * KP;
            if (p >= 2 && t0 < T) {
                #pragma unroll 1
                for (int k = 0; k < KP; ++k) {
                    const int t = t0 + k;
                    if (t >= T) break;
                    const int s = t & (NS - 1);
                    const float x0 = xpring[s][0][lane];        // issued early,
                    const float x1 = xpring[s][1][lane];        // consumed after dots
                    const float x2 = xpring[s][2][lane];
                    const float x3 = xpring[s][3][lane];
                    const h8* hp = (const h8*)h1ring[(t + NS - 1) & (NS - 1)];
                    float a00 = 0.f, a01 = 0.f, a10 = 0.f, a11 = 0.f;
                    float a20 = 0.f, a21 = 0.f, a30 = 0.f, a31 = 0.f;
                    DOTW4(hp, pA, pB, pC, pD);
                    const float ai = x0 + a00 + a01;
                    const float af = x1 + a10 + a11;
                    const float ag = x2 + a20 + a21;
                    const float ao = x3 + a30 + a31;
                    const float iv = fsig(ai), fv = fsig(af);
                    const float gv = ftanh_fast(ag), ov = fsig(ao);
                    cst = fmaf(fv, cst, iv * gv);
                    const float h = ov * ftanh_fast(cst);
                    h1ring[s][lane] = (_Float16)h;
                    h1f32[s][lane]  = h;                        // f32 h for output head
                }
            }
            __syncthreads();
        }
    } else if (wave == 2) {
        // ============ B0: layer-1 xproj, gates i,f (lag 1 phase) ============
        const h8* pA = (const h8*)(wfX + (size_t)lane * HD);
        const h8* pB = (const h8*)(wfX + (size_t)(64 + lane) * HD);
        const float b0 = bih1[lane]      + bhh1[lane];
        const float b1 = bih1[64 + lane] + bhh1[64 + lane];
        __syncthreads();

        for (int p = 0; p < nphase; ++p) {
            const int t0 = (p - 1) * KP;
            if (p >= 1 && t0 < T) {
                #pragma unroll 1
                for (int k = 0; k < KP; ++k) {
                    const int t = t0 + k;
                    if (t >= T) break;
                    const int s = t & (NS - 1);
                    const h8* hp = (const h8*)h0ring[s];
                    float a00 = b0, a01 = 0.f, a10 = b1, a11 = 0.f;
                    DOTW2(hp, pA, pB);
                    xpring[s][0][lane] = a00 + a01;
                    xpring[s][1][lane] = a10 + a11;
                }
            }
            __syncthreads();
        }
    } else {
        // ====== B1: layer-1 xproj, gates g,o (lag 1) + output head (lag 3) ======
        const h8* pA = (const h8*)(wfX + (size_t)(128 + lane) * HD);
        const h8* pB = (const h8*)(wfX + (size_t)(192 + lane) * HD);
        const float b2 = bih1[128 + lane] + bhh1[128 + lane];
        const float b3 = bih1[192 + lane] + bhh1[192 + lane];
        const float blin0 = blin[0];
        __syncthreads();

        for (int p = 0; p < nphase; ++p) {
            const int t0 = (p - 1) * KP;
            if (p >= 1 && t0 < T) {
                #pragma unroll 1
                for (int k = 0; k < KP; ++k) {
                    const int t = t0 + k;
                    if (t >= T) break;
                    const int s = t & (NS - 1);
                    const h8* hp = (const h8*)h0ring[s];
                    float a00 = b2, a01 = 0.f, a10 = b3, a11 = 0.f;
                    DOTW2(hp, pA, pB);
                    xpring[s][2][lane] = a00 + a01;
                    xpring[s][3][lane] = a10 + a11;
                }
            }
            const int t0h = (p - 3) * KP;
            if (p >= 3 && t0h < T && lane < KP) {
                const int t = t0h + lane;
                if (t < T) {
                    const float4* hv4 = (const float4*)h1f32[t & (NS - 1)];
                    const float4* wp  = (const float4*)Wlin;
                    float acc = blin0;
                    #pragma unroll
                    for (int q = 0; q < 16; ++q) {
                        const float4 hv = hv4[q];
                        const float4 wv = wp[q];
                        acc = fmaf(wv.x, hv.x, acc);
                        acc = fmaf(wv.y, hv.y, acc);
                        acc = fmaf(wv.z, hv.z, acc);
                        acc = fmaf(wv.w, hv.w, acc);
                    }
                    out[(size_t)b * T + t] = acc;
                }
            }
            __syncthreads();
        }
    }
}

extern "C" void kernel_launch(void* const* d_in, const int* in_sizes, int n_in,
                              void* d_out, int out_size, void* d_ws, size_t ws_size,
                              hipStream_t stream)
{
    const float* x    = (const float*)d_in[0];
    const float* h0   = (const float*)d_in[1];
    const float* c0   = (const float*)d_in[2];
    const float* Wih0 = (const float*)d_in[3];
    const float* Whh0 = (const float*)d_in[4];
    const float* bih0 = (const float*)d_in[5];
    const float* bhh0 = (const float*)d_in[6];
    const float* Wih1 = (const float*)d_in[7];
    const float* Whh1 = (const float*)d_in[8];
    const float* bih1 = (const float*)d_in[9];
    const float* bhh1 = (const float*)d_in[10];
    const float* Wlin = (const float*)d_in[11];
    const float* blin = (const float*)d_in[12];
    float* out = (float*)d_out;
    _Float16* wf = (_Float16*)d_ws;            // 3 x 16384 f16 = 96 KB

    const int B = in_sizes[1] / (2 * HD);   // h0 is [2,B,HD]
    const int T = in_sizes[0] / B;          // input is [B,T]

    prep_kernel<<<dim3(64), dim3(256), 0, stream>>>(Whh0, Whh1, Wih1, wf);
    lstm2_kernel<<<dim3(B), dim3(256), 0, stream>>>(
        x, h0, c0, Wih0, bih0, bhh0,
        bih1, bhh1, Wlin, blin, wf, out, B, T);
}